// Round 10
// baseline (768.517 us; speedup 1.0000x reference)
//
#include <hip/hip_runtime.h>
#include <cmath>

// ---------------------------------------------------------------------------
// TimestepVisionTransformer — Round 9: full NHWC f16 MFMA decoder.
// All convs = k_convm (generalized from r7-verified k_conv1); LN bridges =
// templated stats/apply (generalized from r8-verified ln1 pair); final conv
// NHWC vectorized. Transformer part unchanged (verified r6-r8).
// B=128, IMG=224, P=16, C_IN=1, E=96, H=4, d=24, NAX=14, N=196, M=B*N=25088
// ---------------------------------------------------------------------------

#define B_   128
#define NPATCH 196
#define M_ROWS (B_*NPATCH)     // 25088
#define E_   96
#define KS   4
#define SEG  49

typedef _Float16 half8 __attribute__((ext_vector_type(8)));
typedef _Float16 half4v __attribute__((ext_vector_type(4)));
typedef float f32x4 __attribute__((ext_vector_type(4)));

// ---------------------------------------------------------------------------
// time embedding
// ---------------------------------------------------------------------------
__global__ void k_time(const float* __restrict__ ts,
                       const float* __restrict__ Wt1, const float* __restrict__ bt1,
                       const float* __restrict__ Wt2, const float* __restrict__ bt2,
                       float* __restrict__ timev)
{
    __shared__ float h[128];
    float e = 0.69314718055994530942f * ts[0];
    float sv = sinf(e), cv = cosf(e);
    int t = threadIdx.x;
    float z = sv * Wt1[t] + cv * Wt1[128 + t] + bt1[t];
    h[t] = z / (1.f + expf(-z));
    __syncthreads();
    if (t < 96) {
        float acc = bt2[t];
        for (int j = 0; j < 128; ++j) acc += h[j] * Wt2[j * 96 + t];
        timev[t] = acc;
    }
}

// ---------------------------------------------------------------------------
// conv weights -> f16 B-layout Wc[layer][p][o][k=tap*CIN+ci], partial N-tiles
// zero-padded (L2: 24->32 rows, L3: 12->16 rows). Final conv -> fp32 wcf.
// halves: L1 [0,73728) L2 [73728,98304) L3 [98304,104448) final [104448,104640)
// tap map (HW-verified via r7 conv1): wy=(tap<2)?(3-ry):(1-ry), wx=(tap&1)?(1-rx):(3-rx)
// ---------------------------------------------------------------------------
__global__ void __launch_bounds__(256) k_wcvtc_all(const float* __restrict__ w1,
                                                   const float* __restrict__ w2,
                                                   const float* __restrict__ w3,
                                                   const float* __restrict__ w4f,
                                                   _Float16* __restrict__ wc,
                                                   float* __restrict__ wcf)
{
    int i = blockIdx.x * 256 + threadIdx.x;
    if (i >= 104640) return;
    if (i >= 104448) {
        int e = i - 104448;
        int p = e / 48, k = e % 48;
        int tap = k / 12, ci = k % 12;
        int ry = p >> 1, rx = p & 1;
        int wy = (tap < 2) ? (3 - ry) : (1 - ry);
        int wx = (tap & 1) ? (1 - rx) : (3 - rx);
        wcf[e] = w4f[ci * 16 + wy * 4 + wx];
        return;
    }
    const float* src; int CIN, COUT, NTR, base;
    if (i < 73728)      { src = w1; CIN = 96; COUT = 48; NTR = 48; base = 0; }
    else if (i < 98304) { src = w2; CIN = 48; COUT = 24; NTR = 32; base = 73728; }
    else                { src = w3; CIN = 24; COUT = 12; NTR = 16; base = 98304; }
    int e = i - base;
    int K = 4 * CIN;
    int perp = NTR * K;
    int p = e / perp, rem = e % perp;
    int o = rem / K, k = rem % K;
    int tap = k / CIN, ci = k % CIN;
    int ry = p >> 1, rx = p & 1;
    int wy = (tap < 2) ? (3 - ry) : (1 - ry);
    int wx = (tap & 1) ? (1 - rx) : (3 - rx);
    wc[i] = (o < COUT) ? (_Float16)src[(ci * COUT + o) * 16 + wy * 4 + wx]
                       : (_Float16)0.f;
}

// ---------------------------------------------------------------------------
// transformer weight convert+transpose to half: Wt[n][k] = W[k][n]
// ---------------------------------------------------------------------------
__global__ void __launch_bounds__(256) k_wcvt(const float* __restrict__ qkv0,
                                              const float* __restrict__ qkv1,
                                              const float* __restrict__ wo0,
                                              const float* __restrict__ wo1,
                                              const float* __restrict__ wm0,
                                              const float* __restrict__ wm1,
                                              const float* __restrict__ wm2,
                                              _Float16* __restrict__ wh)
{
    int i = blockIdx.x * 256 + threadIdx.x;
    const float* src; int N; int e;
    if      (i < 27648)  { src = qkv0; N = 288; e = i; }
    else if (i < 55296)  { src = qkv1; N = 288; e = i - 27648; }
    else if (i < 64512)  { src = wo0;  N = 96;  e = i - 55296; }
    else if (i < 73728)  { src = wo1;  N = 96;  e = i - 64512; }
    else if (i < 82944)  { src = wm0;  N = 96;  e = i - 73728; }
    else if (i < 92160)  { src = wm1;  N = 96;  e = i - 82944; }
    else if (i < 101376) { src = wm2;  N = 96;  e = i - 92160; }
    else return;
    int n = e / 96, k = e % 96;
    wh[i] = (_Float16)src[k * N + n];
}

// ---------------------------------------------------------------------------
// zero the borders of xinh NHWC f16 [b][16][16][96]
// ---------------------------------------------------------------------------
__global__ void __launch_bounds__(256) k_zb_h(_Float16* __restrict__ xinh)
{
    int i = blockIdx.x * 256 + threadIdx.x;
    if (i >= 128 * 60 * 96) return;
    int b = i / 5760, r = i % 5760;
    int pos = r / 96, ch = r % 96;
    int py, px;
    if      (pos < 16) { py = 0;        px = pos; }
    else if (pos < 32) { py = 15;       px = pos - 16; }
    else if (pos < 46) { py = pos - 31; px = 0; }
    else               { py = pos - 45; px = 15; }
    xinh[((size_t)(b * 256) + py * 16 + px) * 96 + ch] = (_Float16)0.f;
}

// ---------------------------------------------------------------------------
// patch embed GEMM via f16 MFMA (r7, verified)
// ---------------------------------------------------------------------------
__global__ void __launch_bounds__(256) k_patch_mfma(const float* __restrict__ x,
                                                    const float* __restrict__ Wp,
                                                    const float* __restrict__ bp,
                                                    float* __restrict__ out)
{
    __shared__ __align__(16) _Float16 Ah[64 * 136];
    __shared__ __align__(16) _Float16 Wh[96 * 136];
    int t = threadIdx.x;
    int p0 = blockIdx.x * 64;
    int wave = t >> 6, lane = t & 63;
    int lm = lane & 15, quad = lane >> 4;
    f32x4 acc[6];
    #pragma unroll
    for (int nt = 0; nt < 6; ++nt) acc[nt] = (f32x4){0.f, 0.f, 0.f, 0.f};

    for (int kc = 0; kc < 2; ++kc) {
        __syncthreads();
        for (int i = t; i < 512; i += 256) {
            int lp = i >> 3, pyl = i & 7;
            int patch = p0 + lp;
            int b = patch / NPATCH, n = patch % NPATCH;
            int ny = n / 14, nx = n % 14;
            const float4* s4 = (const float4*)(x +
                ((size_t)(b * 224) + ny * 16 + kc * 8 + pyl) * 224 + nx * 16);
            float4 v0 = s4[0], v1 = s4[1], v2 = s4[2], v3 = s4[3];
            half8 h0, h1;
            h0[0]=(_Float16)v0.x; h0[1]=(_Float16)v0.y; h0[2]=(_Float16)v0.z; h0[3]=(_Float16)v0.w;
            h0[4]=(_Float16)v1.x; h0[5]=(_Float16)v1.y; h0[6]=(_Float16)v1.z; h0[7]=(_Float16)v1.w;
            h1[0]=(_Float16)v2.x; h1[1]=(_Float16)v2.y; h1[2]=(_Float16)v2.z; h1[3]=(_Float16)v2.w;
            h1[4]=(_Float16)v3.x; h1[5]=(_Float16)v3.y; h1[6]=(_Float16)v3.z; h1[7]=(_Float16)v3.w;
            *(half8*)&Ah[lp * 136 + pyl * 16]     = h0;
            *(half8*)&Ah[lp * 136 + pyl * 16 + 8] = h1;
        }
        for (int i = t; i < 1536; i += 256) {
            int e = i >> 4, s = i & 15;
            const float4* s4 = (const float4*)(Wp + e * 256 + kc * 128 + s * 8);
            float4 v0 = s4[0], v1 = s4[1];
            half8 h0;
            h0[0]=(_Float16)v0.x; h0[1]=(_Float16)v0.y; h0[2]=(_Float16)v0.z; h0[3]=(_Float16)v0.w;
            h0[4]=(_Float16)v1.x; h0[5]=(_Float16)v1.y; h0[6]=(_Float16)v1.z; h0[7]=(_Float16)v1.w;
            *(half8*)&Wh[e * 136 + s * 8] = h0;
        }
        __syncthreads();
        half8 af[4];
        #pragma unroll
        for (int ks = 0; ks < 4; ++ks)
            af[ks] = *(const half8*)&Ah[(wave * 16 + lm) * 136 + ks * 32 + quad * 8];
        #pragma unroll
        for (int ks = 0; ks < 4; ++ks) {
            #pragma unroll
            for (int nt = 0; nt < 6; ++nt) {
                half8 bf = *(const half8*)&Wh[(nt * 16 + lm) * 136 + ks * 32 + quad * 8];
                acc[nt] = __builtin_amdgcn_mfma_f32_16x16x32_f16(af[ks], bf, acc[nt], 0, 0, 0);
            }
        }
    }

    #pragma unroll
    for (int nt = 0; nt < 6; ++nt) {
        #pragma unroll
        for (int r = 0; r < 4; ++r) {
            int e = nt * 16 + lm;
            int lp = wave * 16 + quad * 4 + r;
            int patch = p0 + lp;
            int n = patch % NPATCH;
            int ny = n / 14, nx = n % 14;
            float yx = (float)(ny + nx);
            float v = acc[nt][r] + bp[e];
            float other = __shfl_xor(v, 1);
            float fi = (float)(e >> 1);
            float theta = expf(fi * (-2.f / 96.f) * 9.210340371976184f);
            float ang = theta * yx;
            float c = cosf(ang), s = sinf(ang);
            float outv = (lm & 1) ? (other * s + v * c) : (v * c - other * s);
            out[(size_t)patch * 96 + e] = outv;
        }
    }
}

// ---------------------------------------------------------------------------
// row LayerNorm over 96, wave per row
// ---------------------------------------------------------------------------
__global__ void __launch_bounds__(256) k_ln_row(const float* __restrict__ x,
                                                const float* __restrict__ g,
                                                const float* __restrict__ bv,
                                                float* __restrict__ out, int M)
{
    int lane = threadIdx.x & 63;
    int gw = (blockIdx.x * 256 + threadIdx.x) >> 6;
    int nw = (gridDim.x * 256) >> 6;
    float g0 = g[lane], b0 = bv[lane];
    float g1 = 0.f, b1 = 0.f;
    if (lane < 32) { g1 = g[64 + lane]; b1 = bv[64 + lane]; }
    for (int r = gw; r < M; r += nw) {
        const float* xr = x + (size_t)r * 96;
        float a = xr[lane];
        float c = (lane < 32) ? xr[64 + lane] : 0.f;
        float s = a + c, q = a * a + c * c;
        #pragma unroll
        for (int off = 32; off; off >>= 1) {
            s += __shfl_xor(s, off);
            q += __shfl_xor(q, off);
        }
        float mu = s * (1.f / 96.f);
        float rstd = rsqrtf(q * (1.f / 96.f) - mu * mu + 1e-5f);
        float* orow = out + (size_t)r * 96;
        orow[lane] = (a - mu) * rstd * g0 + b0;
        if (lane < 32) orow[64 + lane] = (c - mu) * rstd * g1 + b1;
    }
}

// ---------------------------------------------------------------------------
// MFMA row GEMM (r6, verified). OUTH: write f16 NHWC padded xinh instead.
// ---------------------------------------------------------------------------
template<int NCHUNKS, bool SILU, bool RES, bool ADDTIME, bool OUTH>
__global__ void __launch_bounds__(256) k_gemm_mfma(const float* __restrict__ A,
                                                   const _Float16* __restrict__ Wt,
                                                   const float* __restrict__ bias,
                                                   const float* __restrict__ res,
                                                   const float* __restrict__ timev,
                                                   float* __restrict__ out,
                                                   _Float16* __restrict__ outh)
{
    __shared__ __align__(16) _Float16 Ah[64 * 96];
    __shared__ __align__(16) _Float16 Wh[96 * 96];
    constexpr int NTOT = NCHUNKS * 96;
    int t = threadIdx.x;
    size_t row0 = (size_t)blockIdx.x * 64;

    const float4* a4 = (const float4*)(A + row0 * 96);
    for (int i = t; i < 1536; i += 256) {
        float4 v = a4[i];
        half4v hv;
        hv[0] = (_Float16)v.x; hv[1] = (_Float16)v.y;
        hv[2] = (_Float16)v.z; hv[3] = (_Float16)v.w;
        *(half4v*)&Ah[i * 4] = hv;
    }

    int wave = t >> 6, lane = t & 63;
    int lm = lane & 15, quad = lane >> 4;
    const f32x4 vzero = {0.f, 0.f, 0.f, 0.f};

    for (int ch = 0; ch < NCHUNKS; ++ch) {
        __syncthreads();
        {
            const uint4* src = (const uint4*)(Wt + (size_t)ch * 9216);
            uint4* dst = (uint4*)Wh;
            for (int i = t; i < 1152; i += 256) dst[i] = src[i];
        }
        __syncthreads();

        half8 af[3];
        #pragma unroll
        for (int ks = 0; ks < 3; ++ks)
            af[ks] = *(const half8*)&Ah[(wave * 16 + lm) * 96 + ks * 32 + quad * 8];

        f32x4 acc[6];
        #pragma unroll
        for (int ct = 0; ct < 6; ++ct) acc[ct] = vzero;

        #pragma unroll
        for (int ct = 0; ct < 6; ++ct) {
            #pragma unroll
            for (int ks = 0; ks < 3; ++ks) {
                half8 bf = *(const half8*)&Wh[(ct * 16 + lm) * 96 + ks * 32 + quad * 8];
                acc[ct] = __builtin_amdgcn_mfma_f32_16x16x32_f16(af[ks], bf, acc[ct], 0, 0, 0);
            }
        }

        #pragma unroll
        for (int ct = 0; ct < 6; ++ct) {
            #pragma unroll
            for (int r = 0; r < 4; ++r) {
                int lr = wave * 16 + quad * 4 + r;
                size_t row = row0 + lr;
                int lc = ct * 16 + lm;
                int col = ch * 96 + lc;
                float v = acc[ct][r] + bias[col];
                if constexpr (RES)     v += res[row * 96 + lc];
                if constexpr (ADDTIME) v += timev[lc];
                if constexpr (SILU)    v = v / (1.f + expf(-v));
                if constexpr (OUTH) {
                    size_t b = row / NPATCH; int n = (int)(row % NPATCH);
                    int ny = n / 14, nx = n % 14;
                    outh[((b * 256) + (1 + ny) * 16 + (1 + nx)) * 96 + col] = (_Float16)v;
                } else {
                    out[row * NTOT + col] = v;
                }
            }
        }
    }
}

// ---------------------------------------------------------------------------
// attention partials (r4, verified)
// ---------------------------------------------------------------------------
__global__ void __launch_bounds__(256) k_attn_part(const float* __restrict__ qkv,
                                                   float* __restrict__ part)
{
    int blk = blockIdx.x;
    int seg = blk % KS;
    int bh  = blk / KS;
    int b = bh >> 2, h = bh & 3;
    const float* base = qkv + (size_t)b * NPATCH * 288 + h * 24;
    __shared__ __align__(16) float KV[SEG * 48];
    int t = threadIdx.x;
    int k0 = seg * SEG;
    for (int i = t; i < SEG * 48; i += 256) {
        int k = i / 48, j = i % 48;
        KV[i] = base[(size_t)(k0 + k) * 288 + 96 + (j < 24 ? j : j + 72)];
    }
    __syncthreads();

    int q = (t < NPATCH) ? t : 0;
    float qv[24], acc[24];
    const float4* qrow = (const float4*)(base + (size_t)q * 288);
    #pragma unroll
    for (int j = 0; j < 6; ++j) {
        float4 v = qrow[j];
        qv[4 * j] = v.x; qv[4 * j + 1] = v.y; qv[4 * j + 2] = v.z; qv[4 * j + 3] = v.w;
    }
    #pragma unroll
    for (int d = 0; d < 24; ++d) acc[d] = 0.f;
    float sum = 0.f;
    const float scale = 0.2041241452319315f;

    #pragma unroll 2
    for (int k = 0; k < SEG; ++k) {
        const float4* kr = (const float4*)(&KV[k * 48]);
        float s0 = 0.f, s1 = 0.f, s2 = 0.f, s3 = 0.f;
        #pragma unroll
        for (int j = 0; j < 6; ++j) {
            float4 Kv = kr[j];
            s0 += qv[4 * j]     * Kv.x;
            s1 += qv[4 * j + 1] * Kv.y;
            s2 += qv[4 * j + 2] * Kv.z;
            s3 += qv[4 * j + 3] * Kv.w;
        }
        float s = (s0 + s1) + (s2 + s3);
        float p = __expf(fminf(s * scale, 60.f));
        sum += p;
        #pragma unroll
        for (int j = 0; j < 6; ++j) {
            float4 Vv = kr[6 + j];
            acc[4 * j]     += p * Vv.x;
            acc[4 * j + 1] += p * Vv.y;
            acc[4 * j + 2] += p * Vv.z;
            acc[4 * j + 3] += p * Vv.w;
        }
    }

    if (t < NPATCH) {
        float4* pp = (float4*)(part + ((size_t)blk * NPATCH + t) * 28);
        #pragma unroll
        for (int j = 0; j < 6; ++j) {
            float4 v;
            v.x = acc[4 * j]; v.y = acc[4 * j + 1];
            v.z = acc[4 * j + 2]; v.w = acc[4 * j + 3];
            pp[j] = v;
        }
        float4 sv; sv.x = sum; sv.y = 0.f; sv.z = 0.f; sv.w = 0.f;
        pp[6] = sv;
    }
}

// ---------------------------------------------------------------------------
// combine K-split partials
// ---------------------------------------------------------------------------
__global__ void __launch_bounds__(256) k_attn_comb(const float* __restrict__ part,
                                                   float* __restrict__ o)
{
    int idx = blockIdx.x * 256 + threadIdx.x;
    int bh = idx / NPATCH, q = idx % NPATCH;
    int b = bh >> 2, h = bh & 3;
    float acc[24];
    #pragma unroll
    for (int d = 0; d < 24; ++d) acc[d] = 0.f;
    float sum = 0.f;
    #pragma unroll
    for (int s = 0; s < KS; ++s) {
        const float4* pp = (const float4*)(part + ((size_t)(bh * KS + s) * NPATCH + q) * 28);
        #pragma unroll
        for (int j = 0; j < 6; ++j) {
            float4 v = pp[j];
            acc[4 * j]     += v.x;
            acc[4 * j + 1] += v.y;
            acc[4 * j + 2] += v.z;
            acc[4 * j + 3] += v.w;
        }
        sum += pp[6].x;
    }
    float inv = 1.f / sum;
    float4* orow = (float4*)(o + ((size_t)b * NPATCH + q) * 96 + h * 24);
    #pragma unroll
    for (int j = 0; j < 6; ++j) {
        float4 v;
        v.x = acc[4 * j] * inv; v.y = acc[4 * j + 1] * inv;
        v.z = acc[4 * j + 2] * inv; v.w = acc[4 * j + 3] * inv;
        orow[j] = v;
    }
}

// ---------------------------------------------------------------------------
// generalized NHWC f16 MFMA transposed conv (from r7-verified k_conv1).
// input xp NHWC f16 padded [b][HIN+2][HIN+2][CIN]; weights Wc[p][NTR][4*CIN]
// (rows >= COUT zeroed); out NHWC fp32 [b][2HIN][2HIN][COUT] + bias.
// Block = 64 input pixels; per parity p=(ry,rx): im2col A[64][4*CIN] in LDS.
// ---------------------------------------------------------------------------
template<int CIN, int HIN, int COUT, int NTR>
__global__ void __launch_bounds__(256) k_convm(const _Float16* __restrict__ xp,
                                               const _Float16* __restrict__ wc,
                                               const float* __restrict__ bias,
                                               float* __restrict__ outc)
{
    constexpr int HP = HIN + 2;
    constexpr int HO = 2 * HIN;
    constexpr int K  = 4 * CIN;
    constexpr int KSTP = K / 32;
    constexpr int NT = (COUT + 15) / 16;
    constexpr int LROW = K + 8;
    constexpr int CH8 = CIN / 8;
    __shared__ __align__(16) _Float16 Ah[64 * LROW];
    int t = threadIdx.x, blk = blockIdx.x;
    int wave = t >> 6, lane = t & 63;
    int lm = lane & 15, quad = lane >> 4;

    for (int p = 0; p < 4; ++p) {
        int ry = p >> 1, rx = p & 1;
        __syncthreads();
        for (int i = t; i < 64 * 4 * CH8; i += 256) {
            int lp = i / (4 * CH8), rem = i % (4 * CH8);
            int tap = rem / CH8, cho = rem % CH8;
            int gp = blk * 64 + lp;
            int b = gp / (HIN * HIN), pix = gp % (HIN * HIN);
            int py = pix / HIN, px = pix % HIN;
            int row = py + ry + (tap >> 1), col = px + rx + (tap & 1);
            const uint4* src = (const uint4*)(xp +
                (((size_t)b * HP + row) * HP + col) * CIN + cho * 8);
            *(uint4*)&Ah[lp * LROW + tap * CIN + cho * 8] = *src;
        }
        __syncthreads();

        f32x4 acc[NT];
        #pragma unroll
        for (int nt = 0; nt < NT; ++nt) acc[nt] = (f32x4){0.f, 0.f, 0.f, 0.f};
        #pragma unroll
        for (int ks = 0; ks < KSTP; ++ks) {
            half8 af = *(const half8*)&Ah[(wave * 16 + lm) * LROW + ks * 32 + quad * 8];
            #pragma unroll
            for (int nt = 0; nt < NT; ++nt) {
                half8 bf = *(const half8*)&wc[((size_t)(p * NTR + nt * 16 + lm)) * K
                                              + ks * 32 + quad * 8];
                acc[nt] = __builtin_amdgcn_mfma_f32_16x16x32_f16(af, bf, acc[nt], 0, 0, 0);
            }
        }
        #pragma unroll
        for (int nt = 0; nt < NT; ++nt) {
            int o = nt * 16 + lm;
            if (o < COUT) {
                #pragma unroll
                for (int r = 0; r < 4; ++r) {
                    int lp = wave * 16 + quad * 4 + r;
                    int gp = blk * 64 + lp;
                    int b = gp / (HIN * HIN), pix = gp % (HIN * HIN);
                    int py = pix / HIN, px = pix % HIN;
                    int oy = 2 * py + ry, ox = 2 * px + rx;
                    outc[((size_t)(b * HO + oy) * HO + ox) * COUT + o] = acc[nt][r] + bias[o];
                }
            }
        }
    }
}

// ---------------------------------------------------------------------------
// NHWC spatial LN stats: one wave per (b,ch) -> stat[b*C+ch] = {mu, rstd}
// grid = B*C/4 blocks (4 waves each).
// ---------------------------------------------------------------------------
template<int C, int HW>
__global__ void __launch_bounds__(256) k_lnc_stats(const float* __restrict__ src,
                                                   float* __restrict__ stat)
{
    int idx = blockIdx.x * 4 + (threadIdx.x >> 6);
    int lane = threadIdx.x & 63;
    int b = idx / C, ch = idx % C;
    const float* base = src + (size_t)b * HW * C + ch;
    float s = 0.f, q = 0.f;
    for (int pix = lane; pix < HW; pix += 64) {
        float v = base[(size_t)pix * C];
        s += v; q += v * v;
    }
    #pragma unroll
    for (int off = 32; off; off >>= 1) {
        s += __shfl_xor(s, off);
        q += __shfl_xor(q, off);
    }
    if (lane == 0) {
        float mu = s / (float)HW;
        float rstd = rsqrtf(q / (float)HW - mu * mu + 1e-5f);
        stat[idx * 2]     = mu;
        stat[idx * 2 + 1] = rstd;
    }
}

// ---------------------------------------------------------------------------
// NHWC LN apply + silu -> next conv's NHWC f16 padded input (borders zeroed).
// one thread per padded NHWC element; fully coalesced read+write.
// ---------------------------------------------------------------------------
template<int C, int H>
__global__ void __launch_bounds__(256) k_lnc_apply(const float* __restrict__ src,
                                                   const float* __restrict__ stat,
                                                   const float* __restrict__ g,
                                                   const float* __restrict__ bv,
                                                   _Float16* __restrict__ dst)
{
    constexpr int HP = H + 2;
    int i = blockIdx.x * 256 + threadIdx.x;
    int b = i / (HP * HP * C);
    int rem = i % (HP * HP * C);
    int pos = rem / C, ch = rem % C;
    int py = pos / HP, px = pos % HP;
    float v = 0.f;
    if (py >= 1 && py <= H && px >= 1 && px <= H) {
        int j = (py - 1) * H + (px - 1);
        float mu = stat[(b * C + ch) * 2], rstd = stat[(b * C + ch) * 2 + 1];
        float u = (src[((size_t)b * H * H + j) * C + ch] - mu) * rstd * g[j] + bv[j];
        v = u / (1.f + expf(-u));
    }
    dst[i] = (_Float16)v;
}

// ---------------------------------------------------------------------------
// final convT 12->1 NHWC: thread = (b, input pixel) computing the 2x2 quad.
// input xpf NHWC f16 padded [b][114][114][12]; weights wcf fp32 [p][tap*12+ci]
// (s_load uniform); silu + clip; out [b][224][224].
// ---------------------------------------------------------------------------
__global__ void __launch_bounds__(256) k_convf_h(const _Float16* __restrict__ xpf,
                                                 const float* __restrict__ wcf,
                                                 const float* __restrict__ bias,
                                                 float* __restrict__ out)
{
    int idx = blockIdx.x * 256 + threadIdx.x;
    int b = idx / 12544;
    int pix = idx % 12544;
    int py = pix / 112, px = pix % 112;
    float acc[2][2] = {{0.f, 0.f}, {0.f, 0.f}};
    #pragma unroll
    for (int dy = 0; dy < 3; ++dy) {
        #pragma unroll
        for (int dx = 0; dx < 3; ++dx) {
            const half4v* pp = (const half4v*)(xpf +
                (((size_t)b * 114 + py + dy) * 114 + px + dx) * 12);
            half4v h0 = pp[0], h1 = pp[1], h2 = pp[2];
            float pv[12];
            #pragma unroll
            for (int k = 0; k < 4; ++k) {
                pv[k] = (float)h0[k]; pv[4 + k] = (float)h1[k]; pv[8 + k] = (float)h2[k];
            }
            #pragma unroll
            for (int ry = 0; ry < 2; ++ry) {
                int ti = dy - ry;
                if (ti < 0 || ti > 1) continue;
                #pragma unroll
                for (int rx = 0; rx < 2; ++rx) {
                    int tj = dx - rx;
                    if (tj < 0 || tj > 1) continue;
                    const float* wrow = wcf + (2 * ry + rx) * 48 + (2 * ti + tj) * 12;
                    float s = 0.f;
                    #pragma unroll
                    for (int ci = 0; ci < 12; ++ci) s += pv[ci] * wrow[ci];
                    acc[ry][rx] += s;
                }
            }
        }
    }
    float bb = bias[0];
    float u00 = acc[0][0] + bb, u01 = acc[0][1] + bb;
    float u10 = acc[1][0] + bb, u11 = acc[1][1] + bb;
    u00 = u00 / (1.f + expf(-u00));
    u01 = u01 / (1.f + expf(-u01));
    u10 = u10 / (1.f + expf(-u10));
    u11 = u11 / (1.f + expf(-u11));
    float2 v0, v1;
    v0.x = fminf(fmaxf(u00, 0.f), 1.f);
    v0.y = fminf(fmaxf(u01, 0.f), 1.f);
    v1.x = fminf(fmaxf(u10, 0.f), 1.f);
    v1.y = fminf(fmaxf(u11, 0.f), 1.f);
    float* orow = out + (size_t)b * 50176 + (2 * py) * 224 + 2 * px;
    *(float2*)orow = v0;
    *(float2*)(orow + 224) = v1;
}

// ---------------------------------------------------------------------------
// launch
// ---------------------------------------------------------------------------
extern "C" void kernel_launch(void* const* d_in, const int* in_sizes, int n_in,
                              void* d_out, int out_size, void* d_ws, size_t ws_size,
                              hipStream_t stream)
{
    const float* x       = (const float*)d_in[0];
    const float* ts      = (const float*)d_in[1];
    const float* Wp      = (const float*)d_in[2];
    const float* bp      = (const float*)d_in[3];
    const float* Wt1     = (const float*)d_in[4];
    const float* bt1     = (const float*)d_in[5];
    const float* Wt2     = (const float*)d_in[6];
    const float* bt2     = (const float*)d_in[7];
    const float* a0_g    = (const float*)d_in[8];
    const float* a0_b    = (const float*)d_in[9];
    const float* a0_Wqkv = (const float*)d_in[10];
    const float* a0_bqkv = (const float*)d_in[11];
    const float* a0_Wo   = (const float*)d_in[12];
    const float* a0_bo   = (const float*)d_in[13];
    const float* a1_g    = (const float*)d_in[14];
    const float* a1_b    = (const float*)d_in[15];
    const float* a1_Wqkv = (const float*)d_in[16];
    const float* a1_bqkv = (const float*)d_in[17];
    const float* a1_Wo   = (const float*)d_in[18];
    const float* a1_bo   = (const float*)d_in[19];
    const float* Wm0     = (const float*)d_in[20];
    const float* bm0     = (const float*)d_in[21];
    const float* Wm1     = (const float*)d_in[22];
    const float* bm1     = (const float*)d_in[23];
    const float* Wm2     = (const float*)d_in[24];
    const float* bm2     = (const float*)d_in[25];
    const float* Wd1     = (const float*)d_in[26];
    const float* bd1     = (const float*)d_in[27];
    const float* l1g     = (const float*)d_in[28];
    const float* l1b     = (const float*)d_in[29];
    const float* Wd2     = (const float*)d_in[30];
    const float* bd2     = (const float*)d_in[31];
    const float* l2g     = (const float*)d_in[32];
    const float* l2b     = (const float*)d_in[33];
    const float* Wd3     = (const float*)d_in[34];
    const float* bd3     = (const float*)d_in[35];
    const float* l3g     = (const float*)d_in[36];
    const float* l3b     = (const float*)d_in[37];
    const float* Wd4     = (const float*)d_in[38];
    const float* bd4     = (const float*)d_in[39];
    float* out = (float*)d_out;

    // arena (floats); R = 25088*96
    const size_t R = 2408448;
    float* ws   = (float*)d_ws;
    float* tvec = ws;                          // 96
    float* p0   = ws + 512;                    // R
    float* h    = ws + 512 + R;                // R
    float* qkvb = ws + 512 + 2 * R;            // 3R
    float* ob   = ws + 512 + 5 * R;            // R
    float* p1   = ws + 512 + 6 * R;            // R
    float* part = ws + 512 + 7 * R;            // attn partials (45 MB, MHSA only)
    // decoder aliases (liveness-checked):
    _Float16* xinh = (_Float16*)(ws + 512 + 2 * R);        // f16 NHWC 16x16x96 (qkv)
    float*    C1   = ws + 512 + 5 * R;                     // NHWC fp32 28x28x48 (2R)
    _Float16* XP2h = (_Float16*)(ws + 512);                // f16 NHWC 30x30x48 (p0/h)
    float*    C2   = ws + 512 + 2 * R;                     // NHWC fp32 56x56x24 (4R)
    _Float16* XP3h = (_Float16*)(ws + 512 + 7 * R + 5529600); // f16 NHWC 58x58x24
    float*    C3n  = ws + 512;                             // NHWC fp32 112x112x12 (8R)
    _Float16* XPFh = (_Float16*)(ws + 512 + 8 * R);        // f16 NHWC 114x114x12
    const size_t WOFF = 512 + 7 * R + 5529600 + 10334208;
    _Float16* WC   = (_Float16*)(ws + WOFF);               // 104640 halves = 52320 fl
    _Float16* WH   = (_Float16*)(ws + WOFF + 52320);       // 101376 halves = 50688 fl
    float* stat1 = ws + WOFF + 52320 + 50688;              // 12288
    float* stat2 = stat1 + 12288;                          // 6144
    float* stat3 = stat2 + 6144;                           // 3072
    float* wcf   = stat3 + 3072;                           // 192
    const size_t NEED = (WOFF + 52320 + 50688 + 12288 + 6144 + 3072 + 192 + 16)
                        * sizeof(float);
    if (ws_size < NEED) return;

    _Float16* WHqkv0 = WH;
    _Float16* WHqkv1 = WH + 27648;
    _Float16* WHwo0  = WH + 55296;
    _Float16* WHwo1  = WH + 64512;
    _Float16* WHwm0  = WH + 73728;
    _Float16* WHwm1  = WH + 82944;
    _Float16* WHwm2  = WH + 92160;

    k_time<<<1, 128, 0, stream>>>(ts, Wt1, bt1, Wt2, bt2, tvec);
    k_wcvtc_all<<<409, 256, 0, stream>>>(Wd1, Wd2, Wd3, Wd4, WC, wcf);
    k_wcvt<<<396, 256, 0, stream>>>(a0_Wqkv, a1_Wqkv, a0_Wo, a1_Wo,
                                    Wm0, Wm1, Wm2, WH);
    k_patch_mfma<<<M_ROWS / 64, 256, 0, stream>>>(x, Wp, bp, p0);

    // MHSA block 0
    k_ln_row<<<1024, 256, 0, stream>>>(p0, a0_g, a0_b, h, M_ROWS);
    k_gemm_mfma<3, false, false, false, false><<<M_ROWS / 64, 256, 0, stream>>>(
        h, WHqkv0, a0_bqkv, nullptr, nullptr, qkvb, nullptr);
    k_attn_part<<<B_ * 4 * KS, 256, 0, stream>>>(qkvb, part);
    k_attn_comb<<<(B_ * 4 * NPATCH) / 256, 256, 0, stream>>>(part, ob);
    k_gemm_mfma<1, false, true, false, false><<<M_ROWS / 64, 256, 0, stream>>>(
        ob, WHwo0, a0_bo, p0, nullptr, p1, nullptr);

    // MHSA block 1 (+time)
    k_ln_row<<<1024, 256, 0, stream>>>(p1, a1_g, a1_b, h, M_ROWS);
    k_gemm_mfma<3, false, false, false, false><<<M_ROWS / 64, 256, 0, stream>>>(
        h, WHqkv1, a1_bqkv, nullptr, nullptr, qkvb, nullptr);
    k_attn_part<<<B_ * 4 * KS, 256, 0, stream>>>(qkvb, part);
    k_attn_comb<<<(B_ * 4 * NPATCH) / 256, 256, 0, stream>>>(part, ob);
    k_gemm_mfma<1, false, true, true, false><<<M_ROWS / 64, 256, 0, stream>>>(
        ob, WHwo1, a1_bo, p1, tvec, p0, nullptr);

    // qkv region free: zero xinh borders before MLP3 writes interior
    k_zb_h<<<2880, 256, 0, stream>>>(xinh);

    // MLP x3 (silu); last writes f16 NHWC padded xinh
    k_gemm_mfma<1, true, false, false, false><<<M_ROWS / 64, 256, 0, stream>>>(
        p0, WHwm0, bm0, nullptr, nullptr, p1, nullptr);
    k_gemm_mfma<1, true, false, false, false><<<M_ROWS / 64, 256, 0, stream>>>(
        p1, WHwm1, bm1, nullptr, nullptr, p0, nullptr);
    k_gemm_mfma<1, true, false, false, true><<<M_ROWS / 64, 256, 0, stream>>>(
        p0, WHwm2, bm2, nullptr, nullptr, nullptr, xinh);

    // decoder: all NHWC f16 MFMA convs + parallel LN bridges
    k_convm<96, 14, 48, 48><<<392, 256, 0, stream>>>(xinh, WC, bd1, C1);
    k_lnc_stats<48, 784><<<1536, 256, 0, stream>>>(C1, stat1);
    k_lnc_apply<48, 28><<<21600, 256, 0, stream>>>(C1, stat1, l1g, l1b, XP2h);
    k_convm<48, 28, 24, 32><<<1568, 256, 0, stream>>>(XP2h, WC + 73728, bd2, C2);
    k_lnc_stats<24, 3136><<<768, 256, 0, stream>>>(C2, stat2);
    k_lnc_apply<24, 56><<<40368, 256, 0, stream>>>(C2, stat2, l2g, l2b, XP3h);
    k_convm<24, 56, 12, 16><<<6272, 256, 0, stream>>>(XP3h, WC + 98304, bd3, C3n);
    k_lnc_stats<12, 12544><<<384, 256, 0, stream>>>(C3n, stat3);
    k_lnc_apply<12, 112><<<77976, 256, 0, stream>>>(C3n, stat3, l3g, l3b, XPFh);
    k_convf_h<<<6272, 256, 0, stream>>>(XPFh, wcf, bd4, out);
}